// Round 5
// baseline (392.682 us; speedup 1.0000x reference)
//
#include <hip/hip_runtime.h>
#include <hip/hip_bf16.h>

#define N_NODES 100000
#define N_EDGES 1600000

// partition geometry
#define BIN_SHIFT 9
#define NBIN 196                 // ceil(100000 / 512)
#define NBLK 256                 // partition blocks
#define CHUNK 6250               // N_EDGES / NBLK (exact)
#define SCAN_N (NBIN * NBLK)     // 50176

typedef __attribute__((ext_vector_type(8))) short bf16x8;
typedef __attribute__((ext_vector_type(4))) float f32x4;

__device__ inline unsigned short f2bf(float f) {
    union { float f; unsigned u; } v; v.f = f;
    unsigned r = v.u + 0x7FFF + ((v.u >> 16) & 1);   // RNE
    return (unsigned short)(r >> 16);
}
__device__ inline float bf2f(unsigned short h) {
    union { unsigned u; float f; } v; v.u = ((unsigned)h) << 16;
    return v.f;
}

// ---------------- binned partition (CSR build without random global writes) ----------------

__global__ __launch_bounds__(256) void p1_bincnt(const int* __restrict__ row,
                                                 int* __restrict__ cnt) {
    __shared__ int h[NBIN];
    for (int i = threadIdx.x; i < NBIN; i += 256) h[i] = 0;
    __syncthreads();
    int base = blockIdx.x * CHUNK;
    int end = base + CHUNK; if (end > N_EDGES) end = N_EDGES;
    for (int i = base + threadIdx.x; i < end; i += 256)
        atomicAdd(&h[row[i] >> BIN_SHIFT], 1);
    __syncthreads();
    for (int b = threadIdx.x; b < NBIN; b += 256)
        cnt[b * NBLK + blockIdx.x] = h[b];
}

__global__ __launch_bounds__(1024) void p2_scan(const int* __restrict__ cnt,
                                                int* __restrict__ base,
                                                int* __restrict__ rp) {
    __shared__ int s[1024];
    int t = threadIdx.x;
    const int per = SCAN_N / 1024;   // 49, exact
    int lo = t * per, hi = lo + per;
    int sum = 0;
    for (int i = lo; i < hi; ++i) sum += cnt[i];
    s[t] = sum;
    __syncthreads();
    for (int off = 1; off < 1024; off <<= 1) {
        int v = (t >= off) ? s[t - off] : 0;
        __syncthreads();
        s[t] += v;
        __syncthreads();
    }
    int run = s[t] - sum;   // exclusive prefix
    for (int i = lo; i < hi; ++i) { int c = cnt[i]; base[i] = run; run += c; }
    if (t == 0) rp[N_NODES] = N_EDGES;
}

__global__ __launch_bounds__(256) void p3_partition(const int* __restrict__ row,
                                                    const int* __restrict__ col,
                                                    const float* __restrict__ val,
                                                    const int* __restrict__ base,
                                                    int2* __restrict__ bout) {
    __shared__ int cur[NBIN];
    for (int i = threadIdx.x; i < NBIN; i += 256)
        cur[i] = base[i * NBLK + blockIdx.x];
    __syncthreads();
    int lo = blockIdx.x * CHUNK;
    int end = lo + CHUNK; if (end > N_EDGES) end = N_EDGES;
    for (int i = lo + threadIdx.x; i < end; i += 256) {
        int r = row[i];
        int b = r >> BIN_SHIFT;
        int p = atomicAdd(&cur[b], 1);
        int2 rec;
        rec.x = col[i] | ((r & 511) << 17);
        rec.y = __float_as_int(val[i]);
        bout[p] = rec;
    }
}

__global__ __launch_bounds__(256) void p4_binscatter(const int* __restrict__ base,
                                                     const int2* __restrict__ bin_in,
                                                     int* __restrict__ rp,
                                                     int2* __restrict__ erec) {
    __shared__ int cnt[512];
    __shared__ int part[256];
    const int b = blockIdx.x;
    const int t = threadIdx.x;
    const int lo = base[b * NBLK];
    const int hi = (b + 1 < NBIN) ? base[(b + 1) * NBLK] : N_EDGES;

    cnt[t] = 0; cnt[t + 256] = 0;
    __syncthreads();
    for (int e = lo + t; e < hi; e += 256)
        atomicAdd(&cnt[(unsigned)bin_in[e].x >> 17], 1);
    __syncthreads();

    int s0 = cnt[2 * t], s1 = cnt[2 * t + 1];
    int tsum = s0 + s1;
    part[t] = tsum;
    __syncthreads();
    for (int off = 1; off < 256; off <<= 1) {
        int v = (t >= off) ? part[t - off] : 0;
        __syncthreads();
        part[t] += v;
        __syncthreads();
    }
    int run = part[t] - tsum;
    cnt[2 * t] = run;
    cnt[2 * t + 1] = run + s0;

    const int rowbase = b << BIN_SHIFT;
    int r0 = rowbase + 2 * t, r1 = rowbase + 2 * t + 1;
    if (r0 < N_NODES) rp[r0] = lo + run;
    if (r1 < N_NODES) rp[r1] = lo + run + s0;
    __syncthreads();

    for (int e = lo + t; e < hi; e += 256) {
        int2 q = bin_in[e];
        int rl = (unsigned)q.x >> 17;
        int p = lo + atomicAdd(&cnt[rl], 1);
        int2 rec;
        rec.x = q.x & 0x1FFFF;
        rec.y = q.y;
        erec[p] = rec;
    }
}

// ---------------- weight pack ----------------
// Bp[((nt*4 + kb)*64 + lane)*8 + j] = bf16(W[kb*32 + (lane>>4)*8 + j][nt*16 + (lane&15)])
template<int FOUT>
__global__ void pack_w_kernel(const float* __restrict__ W, unsigned short* __restrict__ Bp) {
    int idx = blockIdx.x * blockDim.x + threadIdx.x;
    if (idx >= FOUT * 128) return;
    int j = idx & 7, lane = (idx >> 3) & 63, kb = (idx >> 9) & 3, nt = idx >> 11;
    int k = kb * 32 + (lane >> 4) * 8 + j;
    int col = nt * 16 + (lane & 15);
    Bp[idx] = f2bf(W[k * FOUT + col]);
}

// ---------------- layer-0 GEMM (A = x in f32, cast fused) ----------------

template<int FOUT>
__global__ __launch_bounds__(256) void gemm_mfma_f32A(const float* __restrict__ X,
                                                      const unsigned short* __restrict__ Bp,
                                                      const float* __restrict__ bias,
                                                      unsigned short* __restrict__ Y, int n) {
    const int wave = threadIdx.x >> 6;
    const int lane = threadIdx.x & 63;
    const int l15 = lane & 15, kg = lane >> 4;
    const int nbase = blockIdx.y * 64;
    const int rowTile = blockIdx.x * 128 + wave * 32;

    int r0 = rowTile + l15;      if (r0 >= n) r0 = n - 1;
    int r1 = rowTile + 16 + l15; if (r1 >= n) r1 = n - 1;

    bf16x8 a0[4], a1[4];
    const float* x0 = X + (size_t)r0 * 128 + kg * 8;
    const float* x1 = X + (size_t)r1 * 128 + kg * 8;
    #pragma unroll
    for (int kb = 0; kb < 4; ++kb) {
        float4 u = *reinterpret_cast<const float4*>(x0 + kb * 32);
        float4 v = *reinterpret_cast<const float4*>(x0 + kb * 32 + 4);
        a0[kb] = (bf16x8){(short)f2bf(u.x), (short)f2bf(u.y), (short)f2bf(u.z), (short)f2bf(u.w),
                          (short)f2bf(v.x), (short)f2bf(v.y), (short)f2bf(v.z), (short)f2bf(v.w)};
        float4 p = *reinterpret_cast<const float4*>(x1 + kb * 32);
        float4 q = *reinterpret_cast<const float4*>(x1 + kb * 32 + 4);
        a1[kb] = (bf16x8){(short)f2bf(p.x), (short)f2bf(p.y), (short)f2bf(p.z), (short)f2bf(p.w),
                          (short)f2bf(q.x), (short)f2bf(q.y), (short)f2bf(q.z), (short)f2bf(q.w)};
    }

    f32x4 c0[4], c1[4];
    #pragma unroll
    for (int t = 0; t < 4; ++t) {
        c0[t] = (f32x4){0.f, 0.f, 0.f, 0.f};
        c1[t] = (f32x4){0.f, 0.f, 0.f, 0.f};
    }

    const bf16x8* bpv = reinterpret_cast<const bf16x8*>(Bp);
    #pragma unroll
    for (int nt = 0; nt < 4; ++nt) {
        int ntAbs = (nbase >> 4) + nt;
        const bf16x8* bp = bpv + (size_t)(ntAbs * 4) * 64 + lane;
        #pragma unroll
        for (int kb = 0; kb < 4; ++kb) {
            bf16x8 b = bp[kb * 64];
            c0[nt] = __builtin_amdgcn_mfma_f32_16x16x32_bf16(a0[kb], b, c0[nt], 0, 0, 0);
            c1[nt] = __builtin_amdgcn_mfma_f32_16x16x32_bf16(a1[kb], b, c1[nt], 0, 0, 0);
        }
    }

    #pragma unroll
    for (int nt = 0; nt < 4; ++nt) {
        int col = nbase + nt * 16 + l15;
        float bv = bias[col];
        int rb = rowTile + kg * 4;
        #pragma unroll
        for (int j = 0; j < 4; ++j) {
            int ra = rb + j;
            if (ra < n) Y[(size_t)ra * FOUT + col] = f2bf(c0[nt][j] + bv);
            int rc = rb + 16 + j;
            if (rc < n) Y[(size_t)rc * FOUT + col] = f2bf(c1[nt][j] + bv);
        }
    }
}

// ---------------- fused SpMM(+ReLU) + GEMM ----------------
// block = 512 threads (8 waves), tile = 128 nodes. Wave w owns rows [w*16, w*16+16).
// Phase 1: spmm gather -> f32 acc -> relu -> bf16 pack -> LDS A-tile (stride 136 u16).
// Phase 2: MFMA A-tile x Bp -> +bias -> bf16 Y.

template<int FOUT>
__global__ __launch_bounds__(512, 4) void spmm_gemm_fused(const int* __restrict__ rp,
                                                          const int2* __restrict__ erec,
                                                          const unsigned* __restrict__ G,   // [n][64] u32 (128 bf16)
                                                          const unsigned short* __restrict__ Bp,
                                                          const float* __restrict__ bias,
                                                          unsigned short* __restrict__ Y,
                                                          int n) {
    __shared__ unsigned short A[128 * 136];
    const int wave = threadIdx.x >> 6;
    const int lane = threadIdx.x & 63;
    const int half = lane >> 5;     // which edge slot
    const int f2 = lane & 31;       // covers u32 words 2*f2, 2*f2+1 (features 4*f2..4*f2+3)
    const int tile = blockIdx.x * 128;

    // ---- phase 1: gather 16 rows per wave ----
    for (int i = 0; i < 16; ++i) {
        int lrow = wave * 16 + i;
        int node = tile + lrow;
        float a0 = 0.f, a1 = 0.f, a2 = 0.f, a3 = 0.f;
        if (node < n) {
            int e0 = rp[node], e1 = rp[node + 1];
            int e = e0 + half;
            for (; e + 3 <= e1; e += 4) {   // this half: e and e+2 both valid
                int2 qa = erec[e], qb = erec[e + 2];
                uint2 ga = *reinterpret_cast<const uint2*>(G + (size_t)qa.x * 64 + f2 * 2);
                uint2 gb = *reinterpret_cast<const uint2*>(G + (size_t)qb.x * 64 + f2 * 2);
                float va = __int_as_float(qa.y), vb = __int_as_float(qb.y);
                a0 += va * bf2f((unsigned short)ga.x) + vb * bf2f((unsigned short)gb.x);
                a1 += va * bf2f((unsigned short)(ga.x >> 16)) + vb * bf2f((unsigned short)(gb.x >> 16));
                a2 += va * bf2f((unsigned short)ga.y) + vb * bf2f((unsigned short)gb.y);
                a3 += va * bf2f((unsigned short)(ga.y >> 16)) + vb * bf2f((unsigned short)(gb.y >> 16));
            }
            if (e < e1) {
                int2 q = erec[e];
                uint2 g = *reinterpret_cast<const uint2*>(G + (size_t)q.x * 64 + f2 * 2);
                float v = __int_as_float(q.y);
                a0 += v * bf2f((unsigned short)g.x);
                a1 += v * bf2f((unsigned short)(g.x >> 16));
                a2 += v * bf2f((unsigned short)g.y);
                a3 += v * bf2f((unsigned short)(g.y >> 16));
            }
        }
        // combine halves
        a0 += __shfl_xor(a0, 32);
        a1 += __shfl_xor(a1, 32);
        a2 += __shfl_xor(a2, 32);
        a3 += __shfl_xor(a3, 32);
        if (half == 0) {
            a0 = fmaxf(a0, 0.f); a1 = fmaxf(a1, 0.f);
            a2 = fmaxf(a2, 0.f); a3 = fmaxf(a3, 0.f);
            unsigned p0 = (unsigned)f2bf(a0) | ((unsigned)f2bf(a1) << 16);
            unsigned p1 = (unsigned)f2bf(a2) | ((unsigned)f2bf(a3) << 16);
            uint2 pk; pk.x = p0; pk.y = p1;
            *reinterpret_cast<uint2*>(&A[lrow * 136 + f2 * 4]) = pk;
        }
    }
    __syncthreads();

    // ---- phase 2: MFMA (wave computes its own 16 rows x FOUT) ----
    const int l15 = lane & 15, kg = lane >> 4;
    bf16x8 afr[4];
    const unsigned short* arow = &A[(wave * 16 + l15) * 136 + kg * 8];
    #pragma unroll
    for (int kb = 0; kb < 4; ++kb)
        afr[kb] = *reinterpret_cast<const bf16x8*>(arow + kb * 32);

    constexpr int NT = FOUT / 16;
    f32x4 c[NT];
    #pragma unroll
    for (int nt = 0; nt < NT; ++nt) c[nt] = (f32x4){0.f, 0.f, 0.f, 0.f};

    const bf16x8* bpv = reinterpret_cast<const bf16x8*>(Bp);
    #pragma unroll
    for (int nt = 0; nt < NT; ++nt) {
        const bf16x8* bp = bpv + (size_t)(nt * 4) * 64 + lane;
        #pragma unroll
        for (int kb = 0; kb < 4; ++kb)
            c[nt] = __builtin_amdgcn_mfma_f32_16x16x32_bf16(afr[kb], bp[kb * 64], c[nt], 0, 0, 0);
    }

    #pragma unroll
    for (int nt = 0; nt < NT; ++nt) {
        int col = nt * 16 + l15;
        float bv = bias[col];
        int rb = tile + wave * 16 + kg * 4;
        #pragma unroll
        for (int j = 0; j < 4; ++j) {
            int r = rb + j;
            if (r < n) Y[(size_t)r * FOUT + col] = f2bf(c[nt][j] + bv);
        }
    }
}

// ---------------- last SpMM: F=64, f32 out, no relu; dual-edge half-wave gathers ----------------

__global__ __launch_bounds__(256) void spmm_last(const int* __restrict__ rp,
                                                 const int2* __restrict__ erec,
                                                 const unsigned* __restrict__ G,   // [n][32] u32 (64 bf16)
                                                 float* __restrict__ Y, int n) {
    int node = blockIdx.x * 4 + (threadIdx.x >> 6);
    if (node >= n) return;
    int lane = threadIdx.x & 63;
    int half = lane >> 5;
    int f2 = lane & 31;           // u32 word -> features 2*f2, 2*f2+1
    int e0 = rp[node], e1 = rp[node + 1];
    float a0 = 0.f, a1 = 0.f;
    const unsigned* Gf = G + f2;
    int e = e0 + half;
    for (; e + 3 <= e1; e += 4) {
        int2 qa = erec[e], qb = erec[e + 2];
        unsigned ga = Gf[(size_t)qa.x * 32];
        unsigned gb = Gf[(size_t)qb.x * 32];
        float va = __int_as_float(qa.y), vb = __int_as_float(qb.y);
        a0 += va * bf2f((unsigned short)ga) + vb * bf2f((unsigned short)gb);
        a1 += va * bf2f((unsigned short)(ga >> 16)) + vb * bf2f((unsigned short)(gb >> 16));
    }
    if (e < e1) {
        int2 q = erec[e];
        unsigned g = Gf[(size_t)q.x * 32];
        float v = __int_as_float(q.y);
        a0 += v * bf2f((unsigned short)g);
        a1 += v * bf2f((unsigned short)(g >> 16));
    }
    a0 += __shfl_xor(a0, 32);
    a1 += __shfl_xor(a1, 32);
    if (half == 0) {
        float2 o; o.x = a0; o.y = a1;
        *reinterpret_cast<float2*>(&Y[(size_t)node * 64 + f2 * 2]) = o;
    }
}

// ---------------- launch ----------------

extern "C" void kernel_launch(void* const* d_in, const int* in_sizes, int n_in,
                              void* d_out, int out_size, void* d_ws, size_t ws_size,
                              hipStream_t stream) {
    const float* x    = (const float*)d_in[0];
    const int*   arow = (const int*)d_in[1];
    const int*   acol = (const int*)d_in[2];
    const float* aval = (const float*)d_in[3];
    const float* W0   = (const float*)d_in[4];
    const float* b0   = (const float*)d_in[5];
    const float* W1   = (const float*)d_in[6];
    const float* b1   = (const float*)d_in[7];
    const float* W2   = (const float*)d_in[8];
    const float* b2   = (const float*)d_in[9];
    float* out = (float*)d_out;

    // workspace layout
    unsigned short* hbuf0 = (unsigned short*)d_ws;                      // N*128 u16 (gemm0 out; also layer-2 64-wide out)
    unsigned short* hbuf1 = hbuf0 + (size_t)N_NODES * 128;              // N*128 u16 (fused1 out)
    unsigned short* Bp0  = hbuf1 + (size_t)N_NODES * 128;               // 16384 u16
    unsigned short* Bp1  = Bp0 + 128 * 128;                             // 16384 u16
    unsigned short* Bp2  = Bp1 + 128 * 128;                             // 8192 u16
    int* cnt   = (int*)(Bp2 + 64 * 128);                                // NBIN*NBLK
    int* base  = cnt + SCAN_N;                                          // NBIN*NBLK
    int* rp    = base + SCAN_N;                                         // N+2
    int2* bin_in = (int2*)(rp + N_NODES + 2);                           // E
    int2* erec   = bin_in + N_EDGES;                                    // E

    // partition / CSR build
    p1_bincnt<<<NBLK, 256, 0, stream>>>(arow, cnt);
    p2_scan<<<1, 1024, 0, stream>>>(cnt, base, rp);
    p3_partition<<<NBLK, 256, 0, stream>>>(arow, acol, aval, base, bin_in);
    p4_binscatter<<<NBIN, 256, 0, stream>>>(base, bin_in, rp, erec);

    // weight packs
    pack_w_kernel<128><<<64, 256, 0, stream>>>(W0, Bp0);
    pack_w_kernel<128><<<64, 256, 0, stream>>>(W1, Bp1);
    pack_w_kernel<64><<<32, 256, 0, stream>>>(W2, Bp2);

    dim3 gemm_grid((N_NODES + 127) / 128, 2);
    int fused_grid = (N_NODES + 127) / 128;
    int spmm_grid = (N_NODES + 3) / 4;

    // layer 0 linear (x f32 -> bf16 fused)
    gemm_mfma_f32A<128><<<gemm_grid, 256, 0, stream>>>(x, Bp0, b0, hbuf0, N_NODES);
    // spmm0 + relu + linear1
    spmm_gemm_fused<128><<<fused_grid, 512, 0, stream>>>(rp, erec, (const unsigned*)hbuf0, Bp1, b1, hbuf1, N_NODES);
    // spmm1 + relu + linear2 (64-wide out into hbuf0)
    spmm_gemm_fused<64><<<fused_grid, 512, 0, stream>>>(rp, erec, (const unsigned*)hbuf1, Bp2, b2, hbuf0, N_NODES);
    // spmm2 -> f32 out
    spmm_last<<<spmm_grid, 256, 0, stream>>>(rp, erec, (const unsigned*)hbuf0, out, N_NODES);
}